// Round 6
// baseline (189.182 us; speedup 1.0000x reference)
//
#include <hip/hip_runtime.h>

static constexpr int N = 4096;
static constexpr int D = 8192;
static constexpr int BLOCK = 256;   // 4 waves/block

// Quarter-row per wave, 16384 waves. Each wave streams its 2048-col quarter in
// 4 chunks (2 float4 [+2 int4 labels] per lane per chunk), software-pipelined:
// issue chunk c+1 loads -> sched_barrier -> compute chunk c. Keeps VGPR <= 64
// (8 waves/SIMD) AND loads continuously in flight -- the copy-ubench shape.
// Self-pair kept in ssum/fcnt/diag; combine fixes it analytically.
__global__ __launch_bounds__(BLOCK, 6) void supcon_partial(
    const float* __restrict__ emb,
    const int* __restrict__ labels,
    float4* __restrict__ wsA,          // [N*2] {denom, ssum, fcnt, diag}
    float* __restrict__ wsB)           // [N*2] denom
{
    const int wave = threadIdx.x >> 6;
    const int lane = threadIdx.x & 63;
    const int waveId = blockIdx.x * 4 + wave;
    const int row = waveId >> 2;
    const int q   = waveId & 3;

    const float4* rowp = reinterpret_cast<const float4*>(emb + (size_t)row * D);

    if (q < 2) {
        const int lab_i = labels[row];                  // wave-uniform
        const int4* labp = reinterpret_cast<const int4*>(labels);
        const int base = q * 512 + lane;                // float4 index

        float4 a0 = rowp[base], a1 = rowp[base + 64];
        int4   l0 = labp[base], l1 = labp[base + 64];

        float denom = 0.f, ssum = 0.f, fcnt = 0.f, diag = 0.f;
        #pragma unroll
        for (int c = 0; c < 4; ++c) {
            float4 b0 = {}, b1 = {}; int4 m0 = {}, m1 = {};
            if (c < 3) {                                // issue next chunk NOW
                const int nb = base + (c + 1) * 128;
                b0 = rowp[nb]; b1 = rowp[nb + 64];
                m0 = labp[nb]; m1 = labp[nb + 64];
            }
            __builtin_amdgcn_sched_barrier(0);          // loads stay above compute
            {
                const int j0 = (base + c * 128) * 4;
                const float xs[4] = {a0.x, a0.y, a0.z, a0.w};
                const int   ls[4] = {l0.x, l0.y, l0.z, l0.w};
                #pragma unroll
                for (int k = 0; k < 4; ++k) {
                    float a = __expf(xs[k] * xs[k] * 0.1f);
                    denom += a;
                    float b = __expf(a * 0.1f);
                    bool m = (ls[k] == lab_i);
                    ssum += m ? b : 0.f;
                    fcnt += m ? 1.f : 0.f;
                    diag += (j0 + k == row) ? a : 0.f;
                }
            }
            {
                const int j0 = (base + c * 128 + 64) * 4;
                const float xs[4] = {a1.x, a1.y, a1.z, a1.w};
                const int   ls[4] = {l1.x, l1.y, l1.z, l1.w};
                #pragma unroll
                for (int k = 0; k < 4; ++k) {
                    float a = __expf(xs[k] * xs[k] * 0.1f);
                    denom += a;
                    float b = __expf(a * 0.1f);
                    bool m = (ls[k] == lab_i);
                    ssum += m ? b : 0.f;
                    fcnt += m ? 1.f : 0.f;
                    diag += (j0 + k == row) ? a : 0.f;
                }
            }
            a0 = b0; a1 = b1; l0 = m0; l1 = m1;         // rotation (renamed away)
        }
        #pragma unroll
        for (int off = 32; off > 0; off >>= 1) {
            denom += __shfl_down(denom, off);
            ssum  += __shfl_down(ssum,  off);
            fcnt  += __shfl_down(fcnt,  off);
            diag  += __shfl_down(diag,  off);
        }
        if (lane == 0)
            wsA[row * 2 + q] = make_float4(denom, ssum, fcnt, diag);
    } else {
        const int base = 1024 + (q - 2) * 512 + lane;
        float4 a0 = rowp[base], a1 = rowp[base + 64];
        float denom = 0.f;
        #pragma unroll
        for (int c = 0; c < 4; ++c) {
            float4 b0 = {}, b1 = {};
            if (c < 3) {
                const int nb = base + (c + 1) * 128;
                b0 = rowp[nb]; b1 = rowp[nb + 64];
            }
            __builtin_amdgcn_sched_barrier(0);
            denom += __expf(a0.x * a0.x * 0.1f);
            denom += __expf(a0.y * a0.y * 0.1f);
            denom += __expf(a0.z * a0.z * 0.1f);
            denom += __expf(a0.w * a0.w * 0.1f);
            denom += __expf(a1.x * a1.x * 0.1f);
            denom += __expf(a1.y * a1.y * 0.1f);
            denom += __expf(a1.z * a1.z * 0.1f);
            denom += __expf(a1.w * a1.w * 0.1f);
            a0 = b0; a1 = b1;
        }
        #pragma unroll
        for (int off = 32; off > 0; off >>= 1)
            denom += __shfl_down(denom, off);
        if (lane == 0)
            wsB[row * 2 + (q - 2)] = denom;
    }
}

// Single block: all 4096 rows -> per-row log expr -> full in-block reduce ->
// direct store (no atomic, no memset dispatch needed).
__global__ __launch_bounds__(1024) void supcon_combine(
    const float4* __restrict__ wsA,
    const float* __restrict__ wsB,
    float* __restrict__ out)
{
    const int tid = threadIdx.x;
    float val = 0.f;
    #pragma unroll
    for (int k = 0; k < 4; ++k) {
        const int row = tid + k * 1024;
        const float4 p0 = wsA[row * 2 + 0];
        const float4 p1 = wsA[row * 2 + 1];
        const float b0 = wsB[row * 2 + 0];
        const float b1 = wsB[row * 2 + 1];
        const float ad = p0.w + p1.w;                   // A[i,i]
        const float denom = (p0.x + p1.x + b0 + b1) - ad;
        const float ssum  = (p0.y + p1.y) - __expf(ad * 0.1f);
        const float fcnt  = (p0.z + p1.z) - 1.f;
        val += __logf(ssum) - __logf(denom) - __logf(fcnt);
    }
    #pragma unroll
    for (int off = 32; off > 0; off >>= 1)
        val += __shfl_down(val, off);
    __shared__ float sb[16];
    if ((tid & 63) == 0) sb[tid >> 6] = val;
    __syncthreads();
    if (tid == 0) {
        float t = 0.f;
        #pragma unroll
        for (int w = 0; w < 16; ++w) t += sb[w];
        *out = t;
    }
}

extern "C" void kernel_launch(void* const* d_in, const int* in_sizes, int n_in,
                              void* d_out, int out_size, void* d_ws, size_t ws_size,
                              hipStream_t stream) {
    const float* emb  = (const float*)d_in[0];
    const int* labels = (const int*)d_in[1];
    float* out        = (float*)d_out;

    float4* wsA = (float4*)d_ws;                                   // 128 KB
    float*  wsB = (float*)((char*)d_ws + N * 2 * sizeof(float4));  // 32 KB

    supcon_partial<<<dim3(N), dim3(BLOCK), 0, stream>>>(emb, labels, wsA, wsB);
    supcon_combine<<<dim3(1), dim3(1024), 0, stream>>>(wsA, wsB, out);
}